// Round 14
// baseline (195.362 us; speedup 1.0000x reference)
//
#include <hip/hip_runtime.h>
#include <math.h>

#define N_NODES 50000
#define D 128       // d_in == d_hid
#define D_OUT 64

typedef short bf16x8 __attribute__((ext_vector_type(8)));   // 8 bf16 (4 VGPR) MFMA frag
typedef float f32x4  __attribute__((ext_vector_type(4)));   // MFMA accumulator
typedef unsigned short u16x8 __attribute__((ext_vector_type(8)));

__device__ __forceinline__ unsigned short f_to_bf16(float f) {
    unsigned int u = __float_as_uint(f);
    u = (u + 0x7fffu + ((u >> 16) & 1u)) >> 16;   // RNE
    return (unsigned short)u;
}
__device__ __forceinline__ float bf16f(unsigned short v) { return __uint_as_float((unsigned int)v << 16); }

// ---------------------------------------------------------------------------
// conv helpers: 8 f32 -> 8 bf16 (+ optionally 8 fp8 e4m3)
// ---------------------------------------------------------------------------
__device__ __forceinline__ void conv8(const float* __restrict__ src, unsigned short* __restrict__ dst, int i)
{
    float4 v0 = *reinterpret_cast<const float4*>(src + i);
    float4 v1 = *reinterpret_cast<const float4*>(src + i + 4);
    u16x8 o;
    o[0] = f_to_bf16(v0.x); o[1] = f_to_bf16(v0.y);
    o[2] = f_to_bf16(v0.z); o[3] = f_to_bf16(v0.w);
    o[4] = f_to_bf16(v1.x); o[5] = f_to_bf16(v1.y);
    o[6] = f_to_bf16(v1.z); o[7] = f_to_bf16(v1.w);
    *reinterpret_cast<u16x8*>(dst + i) = o;
}

__device__ __forceinline__ void conv8x(const float* __restrict__ src,
                                       unsigned short* __restrict__ dstb,
                                       unsigned char* __restrict__ dst8, int i)
{
    float4 v0 = *reinterpret_cast<const float4*>(src + i);
    float4 v1 = *reinterpret_cast<const float4*>(src + i + 4);
    u16x8 o;
    o[0] = f_to_bf16(v0.x); o[1] = f_to_bf16(v0.y);
    o[2] = f_to_bf16(v0.z); o[3] = f_to_bf16(v0.w);
    o[4] = f_to_bf16(v1.x); o[5] = f_to_bf16(v1.y);
    o[6] = f_to_bf16(v1.z); o[7] = f_to_bf16(v1.w);
    *reinterpret_cast<u16x8*>(dstb + i) = o;

    uint2 p;
    p.x = __builtin_amdgcn_cvt_pk_fp8_f32(v0.x, v0.y, 0, false);
    p.x = __builtin_amdgcn_cvt_pk_fp8_f32(v0.z, v0.w, p.x, true);
    p.y = __builtin_amdgcn_cvt_pk_fp8_f32(v1.x, v1.y, 0, false);
    p.y = __builtin_amdgcn_cvt_pk_fp8_f32(v1.z, v1.w, p.y, true);
    *reinterpret_cast<uint2*>(dst8 + i) = p;
}

// decode 16 fp8 (one uint4) and accumulate into acc[0..15]
__device__ __forceinline__ void acc_add_fp8(float* acc, uint4 v)
{
    const unsigned int d0 = v.x, d1 = v.y, d2 = v.z, d3 = v.w;
    {
        auto lo = __builtin_amdgcn_cvt_pk_f32_fp8(d0, false);
        auto hi = __builtin_amdgcn_cvt_pk_f32_fp8(d0, true);
        acc[0] += lo[0]; acc[1] += lo[1]; acc[2] += hi[0]; acc[3] += hi[1];
    }
    {
        auto lo = __builtin_amdgcn_cvt_pk_f32_fp8(d1, false);
        auto hi = __builtin_amdgcn_cvt_pk_f32_fp8(d1, true);
        acc[4] += lo[0]; acc[5] += lo[1]; acc[6] += hi[0]; acc[7] += hi[1];
    }
    {
        auto lo = __builtin_amdgcn_cvt_pk_f32_fp8(d2, false);
        auto hi = __builtin_amdgcn_cvt_pk_f32_fp8(d2, true);
        acc[8] += lo[0]; acc[9] += lo[1]; acc[10] += hi[0]; acc[11] += hi[1];
    }
    {
        auto lo = __builtin_amdgcn_cvt_pk_f32_fp8(d3, false);
        auto hi = __builtin_amdgcn_cvt_pk_f32_fp8(d3, true);
        acc[12] += lo[0]; acc[13] += lo[1]; acc[14] += hi[0]; acc[15] += hi[1];
    }
}

__device__ __forceinline__ unsigned char f_to_fp8(float v)
{
    return (unsigned char)(__builtin_amdgcn_cvt_pk_fp8_f32(v, v, 0, false) & 0xFF);
}

// ---------------------------------------------------------------------------
// Zero deg|cursor
// ---------------------------------------------------------------------------
__global__ __launch_bounds__(256) void zero_kernel(int* __restrict__ p, int n4)
{
    int i = blockIdx.x * 256 + threadIdx.x;
    if (i < n4) *reinterpret_cast<int4*>(p + i * 4) = make_int4(0, 0, 0, 0);
}

// ---------------------------------------------------------------------------
// Fused prep: conv_x (bf16 + fp8) | conv_w | hist, dispatched by block range.
// ---------------------------------------------------------------------------
__global__ __launch_bounds__(256) void prep_kernel(
    const float* __restrict__ x, unsigned short* __restrict__ xb,
    unsigned char* __restrict__ x8,
    const float* __restrict__ w1l, const float* __restrict__ w1r,
    const float* __restrict__ w2l, const float* __restrict__ w2r,
    unsigned short* __restrict__ Wb,
    const int* __restrict__ dst, int* __restrict__ deg,
    int XB, int E)
{
    const int bx = blockIdx.x;
    if (bx < XB) {
        int i = (bx * 256 + threadIdx.x) * 8;
        if (i < N_NODES * D) conv8x(x, xb, x8, i);
    } else if (bx < XB + 24) {
        int i = ((bx - XB) * 256 + threadIdx.x) * 8;   // 49152 elems
        const float* src; int off;
        if      (i < 16384) { src = w1l; off = 0; }
        else if (i < 32768) { src = w1r; off = 16384; }
        else if (i < 40960) { src = w2l; off = 32768; }
        else                { src = w2r; off = 40960; }
        conv8(src, Wb + off, i - off);
    } else {
        int e = (bx - XB - 24) * 256 + threadIdx.x;
        if (e < E) atomicAdd(&deg[dst[e]], 1);
    }
}

// ---------------------------------------------------------------------------
// Scan step 1: per-block (1024 elems) local exclusive scan + block sums
// ---------------------------------------------------------------------------
__global__ __launch_bounds__(256) void scan1_kernel(
    const int* __restrict__ deg, int* __restrict__ part,
    int* __restrict__ bsum, int n)
{
    const int t = threadIdx.x;
    const int base = blockIdx.x * 1024 + t * 4;

    int a0 = 0, a1 = 0, a2 = 0, a3 = 0;
    if (base + 3 < n) {
        int4 v = *reinterpret_cast<const int4*>(deg + base);
        a0 = v.x; a1 = v.y; a2 = v.z; a3 = v.w;
    } else if (base < n) {
        a0 = deg[base];
        if (base + 1 < n) a1 = deg[base + 1];
        if (base + 2 < n) a2 = deg[base + 2];
    }
    const int s0 = a0, s1 = s0 + a1, s2 = s1 + a2, s3 = s2 + a3;

    const int lane = t & 63;
    int incl = s3;
#pragma unroll
    for (int off = 1; off < 64; off <<= 1) {
        int up = __shfl_up(incl, off);
        if (lane >= off) incl += up;
    }

    __shared__ int wsum[4];
    const int wid = t >> 6;
    if (lane == 63) wsum[wid] = incl;
    __syncthreads();

    int woff = 0;
#pragma unroll
    for (int w = 0; w < 4; ++w) woff += (w < wid) ? wsum[w] : 0;

    const int ex = woff + incl - s3;
    if (base + 3 < n) {
        int4 o; o.x = ex; o.y = ex + s0; o.z = ex + s1; o.w = ex + s2;
        *reinterpret_cast<int4*>(part + base) = o;
    } else if (base < n) {
        part[base] = ex;
        if (base + 1 < n) part[base + 1] = ex + s0;
        if (base + 2 < n) part[base + 2] = ex + s1;
    }
    if (t == 255) bsum[blockIdx.x] = woff + incl;
}

// ---------------------------------------------------------------------------
// Scan step 2: per-block offset from 49 block sums (64-lane masked reduce),
// part + offset -> row_ptr; last block writes row_ptr[n].
// ---------------------------------------------------------------------------
__global__ __launch_bounds__(256) void scan3_kernel(
    const int* __restrict__ part, const int* __restrict__ bsum,
    int* __restrict__ row_ptr, int nb, int n)
{
    __shared__ int sAdd, sTot;
    const int t = threadIdx.x;
    const int bid = blockIdx.x;

    if (t < 64) {
        int v   = (t < nb) ? bsum[t] : 0;
        int add = (t < bid) ? v : 0;
        int tot = v;
#pragma unroll
        for (int off = 1; off < 64; off <<= 1) {
            add += __shfl_xor(add, off);
            tot += __shfl_xor(tot, off);
        }
        if (t == 0) { sAdd = add; sTot = tot; }
    }
    __syncthreads();

    const int add = sAdd;
    const int base = bid * 1024 + t * 4;
    if (base + 3 < n) {
        int4 v = *reinterpret_cast<const int4*>(part + base);
        v.x += add; v.y += add; v.z += add; v.w += add;
        *reinterpret_cast<int4*>(row_ptr + base) = v;
    } else if (base < n) {
        row_ptr[base] = part[base] + add;
        if (base + 1 < n) row_ptr[base + 1] = part[base + 1] + add;
        if (base + 2 < n) row_ptr[base + 2] = part[base + 2] + add;
    }
    if (bid == nb - 1 && t == 0) row_ptr[n] = sTot;
}

// ---------------------------------------------------------------------------
// CSR bucket-fill
// ---------------------------------------------------------------------------
__global__ __launch_bounds__(256) void fill_kernel(
    const int* __restrict__ src, const int* __restrict__ dst,
    const int* __restrict__ row_ptr, int* __restrict__ cursor,
    int* __restrict__ esrc, int E)
{
    int e = blockIdx.x * blockDim.x + threadIdx.x;
    if (e >= E) return;
    int d = dst[e];
    int pos = atomicAdd(&cursor[d], 1);
    esrc[row_ptr[d] + pos] = src[e];
}

// ---------------------------------------------------------------------------
// fp8 gather-aggregate, 1 wave/node (4 waves/block), templated on CHUNKS
// (uint4 chunks per fp8 row; row elems = CHUNKS*16, row bytes = CHUNKS*16).
//   CHUNKS=8 (x8, 128B rows):  RPL=8,  NLOADS=4 -> 32 rows/iter
//   CHUNKS=4 (t28, 64B rows):  RPL=16, NLOADS=4 -> 64 rows/iter
// Accumulates f32 (16 elems/lane), writes premeaned bf16 row.
// ---------------------------------------------------------------------------
template<int CHUNKS>
__global__ __launch_bounds__(256) void gather_fp8_kernel(
    const unsigned char* __restrict__ x8,
    const int* __restrict__ row_ptr,
    const int* __restrict__ esrc,
    unsigned short* __restrict__ aggb,   // [n][CHUNKS*16] bf16
    int n_nodes)
{
    constexpr int RPL = 64 / CHUNKS;        // rows per load instr
    constexpr int NLOADS = 4;               // predicated loads per iter
    constexpr int ITER = RPL * NLOADS;
    const int wv   = threadIdx.x >> 6;
    const int lane = threadIdx.x & 63;
    const int node = blockIdx.x * 4 + wv;
    if (node >= n_nodes) return;

    const int beg = row_ptr[node];
    const int end = row_ptr[node + 1];
    const int g = lane / CHUNKS;            // row slot within load
    const int c = lane % CHUNKS;            // 16B chunk within row

    const uint4* x4 = reinterpret_cast<const uint4*>(x8);

    float acc[16];
#pragma unroll
    for (int k = 0; k < 16; ++k) acc[k] = 0.f;

    for (int base = beg; base < end; base += 64) {
        const int cnt = min(end - base, 64);
        int s = (base + lane < end) ? esrc[base + lane] : 0;
        for (int i = 0; i < cnt; i += ITER) {
            int pp[NLOADS]; uint4 vv[NLOADS]; bool ok[NLOADS];
#pragma unroll
            for (int j = 0; j < NLOADS; ++j) {
                pp[j] = i + j * RPL + g;
                int sj = __shfl(s, pp[j] & 63);
                ok[j] = pp[j] < cnt;
                if (ok[j]) vv[j] = x4[(size_t)sj * CHUNKS + c];
            }
#pragma unroll
            for (int j = 0; j < NLOADS; ++j)
                if (ok[j]) acc_add_fp8(acc, vv[j]);
        }
    }

    // combine row-slot groups (lanes sharing chunk c)
#pragma unroll
    for (int k = 0; k < 16; ++k) {
#pragma unroll
        for (int off = CHUNKS; off < 64; off <<= 1)
            acc[k] += __shfl_xor(acc[k], off);
    }

    if (g == 0) {
        const float inv = (end > beg) ? 1.0f / (float)(end - beg) : 0.0f;
        uint4 o0, o1;
        unsigned int w[8];
#pragma unroll
        for (int q = 0; q < 8; ++q)
            w[q] = (unsigned int)f_to_bf16(acc[2 * q] * inv)
                 | ((unsigned int)f_to_bf16(acc[2 * q + 1] * inv) << 16);
        o0.x = w[0]; o0.y = w[1]; o0.z = w[2]; o0.w = w[3];
        o1.x = w[4]; o1.y = w[5]; o1.z = w[6]; o1.w = w[7];
        uint4* out4 = reinterpret_cast<uint4*>(aggb);
        out4[(size_t)node * CHUNKS * 2 + c * 2]     = o0;
        out4[(size_t)node * CHUNKS * 2 + c * 2 + 1] = o1;
    }
}

// ---------------------------------------------------------------------------
// Layer 1 via MFMA 16x16x32 bf16, one wave per 16-node tile.
// Emits t2 = h1 · W2l^T as FP8 [N,64] so layer-2 gathers 64B rows.
// D-layout: col = lane&15, row = (lane>>4)*4 + reg   [m89 verified]
// ---------------------------------------------------------------------------
__global__ __launch_bounds__(64) void layer1_mfma_kernel(
    const unsigned short* __restrict__ aggb,
    const unsigned short* __restrict__ xb,
    const unsigned short* __restrict__ Wb,   // W1l@0, W1r@16384, W2l@32768
    const float* __restrict__ b1,
    unsigned short* __restrict__ h1b,
    unsigned char* __restrict__ t28)         // [N,64] fp8
{
    __shared__ unsigned short h1s[16][144];  // padded: 288B rows, 16B-aligned

    const int lane  = threadIdx.x;
    const int node0 = blockIdx.x * 16;
    const int c16   = lane & 15;
    const int kg    = lane >> 4;

    bf16x8 a[2][4];
    {
        const unsigned short* A0 = aggb + (size_t)(node0 + c16) * D + kg * 8;
        const unsigned short* A1 = xb   + (size_t)(node0 + c16) * D + kg * 8;
#pragma unroll
        for (int kf = 0; kf < 4; ++kf) {
            a[0][kf] = *reinterpret_cast<const bf16x8*>(A0 + kf * 32);
            a[1][kf] = *reinterpret_cast<const bf16x8*>(A1 + kf * 32);
        }
    }
    const unsigned short* WL = Wb;
    const unsigned short* WR = Wb + 16384;

#pragma unroll 2
    for (int jt = 0; jt < 8; ++jt) {
        f32x4 acc = {0.f, 0.f, 0.f, 0.f};
        const unsigned short* wl = WL + (size_t)(jt * 16 + c16) * D + kg * 8;
        const unsigned short* wr = WR + (size_t)(jt * 16 + c16) * D + kg * 8;
#pragma unroll
        for (int kf = 0; kf < 4; ++kf) {
            bf16x8 b = *reinterpret_cast<const bf16x8*>(wl + kf * 32);
            acc = __builtin_amdgcn_mfma_f32_16x16x32_bf16(a[0][kf], b, acc, 0, 0, 0);
        }
#pragma unroll
        for (int kf = 0; kf < 4; ++kf) {
            bf16x8 b = *reinterpret_cast<const bf16x8*>(wr + kf * 32);
            acc = __builtin_amdgcn_mfma_f32_16x16x32_bf16(a[1][kf], b, acc, 0, 0, 0);
        }
        const float bias = b1[jt * 16 + c16];
#pragma unroll
        for (int i = 0; i < 4; ++i) {
            float v = fmaxf(acc[i] + bias, 0.0f);
            unsigned short us = f_to_bf16(v);
            h1b[(size_t)(node0 + kg * 4 + i) * D + jt * 16 + c16] = us;
            h1s[kg * 4 + i][jt * 16 + c16] = us;
        }
    }

    __syncthreads();

    // t2 = h1_tile (16x128) · W2l^T -> 16x64, stored fp8
    bf16x8 a2[4];
#pragma unroll
    for (int kf = 0; kf < 4; ++kf)
        a2[kf] = *reinterpret_cast<const bf16x8*>(&h1s[c16][kg * 8 + kf * 32]);

    const unsigned short* W2L = Wb + 32768;
#pragma unroll
    for (int jt = 0; jt < 4; ++jt) {
        f32x4 acc = {0.f, 0.f, 0.f, 0.f};
        const unsigned short* wl = W2L + (size_t)(jt * 16 + c16) * D + kg * 8;
#pragma unroll
        for (int kf = 0; kf < 4; ++kf) {
            bf16x8 b = *reinterpret_cast<const bf16x8*>(wl + kf * 32);
            acc = __builtin_amdgcn_mfma_f32_16x16x32_bf16(a2[kf], b, acc, 0, 0, 0);
        }
#pragma unroll
        for (int i = 0; i < 4; ++i)
            t28[(size_t)(node0 + kg * 4 + i) * D_OUT + jt * 16 + c16] = f_to_fp8(acc[i]);
    }
}

// ---------------------------------------------------------------------------
// Layer 2: out = log_softmax( agg(t2) + b2 + h1·W2r^T ).
// Left term arrives premeaned in agg2b [N,64] bf16.
// ---------------------------------------------------------------------------
__global__ __launch_bounds__(64) void layer2_mfma_kernel(
    const unsigned short* __restrict__ agg2b,   // [N,64] premeaned t2 (bf16)
    const unsigned short* __restrict__ h1b,
    const unsigned short* __restrict__ Wb,      // W2r@40960
    const float* __restrict__ b2,
    float* __restrict__ out)
{
    const int lane  = threadIdx.x;
    const int node0 = blockIdx.x * 16;
    const int c16   = lane & 15;
    const int kg    = lane >> 4;

    bf16x8 a[4];
    {
        const unsigned short* A1 = h1b + (size_t)(node0 + c16) * D + kg * 8;
#pragma unroll
        for (int kf = 0; kf < 4; ++kf)
            a[kf] = *reinterpret_cast<const bf16x8*>(A1 + kf * 32);
    }
    const unsigned short* WR = Wb + 40960;

    f32x4 accs[4];
#pragma unroll
    for (int jt = 0; jt < 4; ++jt) {
        f32x4 acc = {0.f, 0.f, 0.f, 0.f};
        const unsigned short* wr = WR + (size_t)(jt * 16 + c16) * D + kg * 8;
#pragma unroll
        for (int kf = 0; kf < 4; ++kf) {
            bf16x8 b = *reinterpret_cast<const bf16x8*>(wr + kf * 32);
            acc = __builtin_amdgcn_mfma_f32_16x16x32_bf16(a[kf], b, acc, 0, 0, 0);
        }
        accs[jt] = acc;
    }

    float bias[4];
#pragma unroll
    for (int jt = 0; jt < 4; ++jt) bias[jt] = b2[jt * 16 + c16];

#pragma unroll
    for (int i = 0; i < 4; ++i) {
        const int node = node0 + kg * 4 + i;
        float z[4];
        float m = -1e30f;
#pragma unroll
        for (int jt = 0; jt < 4; ++jt) {
            float lft = bf16f(agg2b[(size_t)node * D_OUT + jt * 16 + c16]);
            z[jt] = lft + accs[jt][i] + bias[jt];
            m = fmaxf(m, z[jt]);
        }
#pragma unroll
        for (int off = 1; off < 16; off <<= 1)
            m = fmaxf(m, __shfl_xor(m, off));
        float s = 0.f;
#pragma unroll
        for (int jt = 0; jt < 4; ++jt) s += expf(z[jt] - m);
#pragma unroll
        for (int off = 1; off < 16; off <<= 1)
            s += __shfl_xor(s, off);
        float lse = m + logf(s);
#pragma unroll
        for (int jt = 0; jt < 4; ++jt)
            out[(size_t)node * D_OUT + jt * 16 + c16] = z[jt] - lse;
    }
}

// ---------------------------------------------------------------------------
extern "C" void kernel_launch(void* const* d_in, const int* in_sizes, int n_in,
                              void* d_out, int out_size, void* d_ws, size_t ws_size,
                              hipStream_t stream)
{
    const float* x   = (const float*)d_in[0];
    const int*   ei  = (const int*)d_in[1];
    const float* W1l = (const float*)d_in[2];
    const float* b1  = (const float*)d_in[3];
    const float* W1r = (const float*)d_in[4];
    const float* W2l = (const float*)d_in[5];
    const float* b2  = (const float*)d_in[6];
    const float* W2r = (const float*)d_in[7];
    float* out = (float*)d_out;

    const int E = in_sizes[1] / 2;
    const int* src = ei;
    const int* dst = ei + E;

    // ---- workspace layout (256B-aligned chunks) ----
    char* base = (char*)d_ws;
    size_t off = 0;
    auto take = [&](size_t bytes) { char* p = base + off; off += (bytes + 255) & ~(size_t)255; return p; };

    unsigned short* xb    = (unsigned short*)take((size_t)N_NODES * D * 2);     // bf16 x
    unsigned char*  x8    = (unsigned char*) take((size_t)N_NODES * D);         // fp8 x
    unsigned short* aggb  = (unsigned short*)take((size_t)N_NODES * D * 2);     // bf16 agg
    unsigned short* h1b   = (unsigned short*)take((size_t)N_NODES * D * 2);     // bf16 h1
    unsigned char*  t28   = (unsigned char*) take((size_t)N_NODES * D_OUT);     // fp8 t2
    unsigned short* agg2b = (unsigned short*)take((size_t)N_NODES * D_OUT * 2); // bf16 agg2
    unsigned short* Wb    = (unsigned short*)take((size_t)49152 * 2);
    int* degcur  = (int*)take((size_t)2 * N_NODES * 4);   // deg | cursor
    int* deg     = degcur;
    int* cursor  = degcur + N_NODES;
    int* row_ptr = (int*)take(((size_t)N_NODES + 1) * 4);
    int* part    = (int*)take((size_t)N_NODES * 4);
    int* bsum    = (int*)take((size_t)64 * 4);
    int* esrc    = (int*)take((size_t)E * 4);

    const int EB = (E + 255) / 256;
    const int SB = (N_NODES + 1023) / 1024;       // 49 scan blocks
    const int XB = (N_NODES * D / 8 + 255) / 256; // 3125 conv_x blocks
    const int GB = (N_NODES + 3) / 4;             // gather: 4 nodes per block
    const int MB = N_NODES / 16;                  // 3125 tile blocks, exact

    zero_kernel<<<(2 * N_NODES / 4 + 255) / 256, 256, 0, stream>>>(degcur, 2 * N_NODES / 4);
    prep_kernel<<<XB + 24 + EB, 256, 0, stream>>>(x, xb, x8, W1l, W1r, W2l, W2r, Wb, dst, deg, XB, E);
    scan1_kernel<<<SB, 256, 0, stream>>>(deg, part, bsum, N_NODES);
    scan3_kernel<<<SB, 256, 0, stream>>>(part, bsum, row_ptr, SB, N_NODES);
    fill_kernel<<<EB, 256, 0, stream>>>(src, dst, row_ptr, cursor, esrc, E);

    // ---- layer 1 (+ t2 = h1·W2l^T in fp8) ----
    gather_fp8_kernel<8><<<GB, 256, 0, stream>>>(x8, row_ptr, esrc, aggb, N_NODES);
    layer1_mfma_kernel<<<MB, 64, 0, stream>>>(aggb, xb, Wb, b1, h1b, t28);

    // ---- layer 2 (gather over 64B fp8 t2 rows) ----
    gather_fp8_kernel<4><<<GB, 256, 0, stream>>>(t28, row_ptr, esrc, agg2b, N_NODES);
    layer2_mfma_kernel<<<MB, 64, 0, stream>>>(agg2b, h1b, Wb, b2, out);
}

// Round 15
// 177.227 us; speedup vs baseline: 1.1023x; 1.1023x over previous
//
#include <hip/hip_runtime.h>
#include <math.h>

#define N_NODES 50000
#define D 128       // d_in == d_hid
#define D_OUT 64

typedef short bf16x8 __attribute__((ext_vector_type(8)));   // 8 bf16 (4 VGPR) MFMA frag
typedef float f32x4  __attribute__((ext_vector_type(4)));   // MFMA accumulator
typedef unsigned short u16x8 __attribute__((ext_vector_type(8)));

__device__ __forceinline__ unsigned short f_to_bf16(float f) {
    unsigned int u = __float_as_uint(f);
    u = (u + 0x7fffu + ((u >> 16) & 1u)) >> 16;   // RNE
    return (unsigned short)u;
}
__device__ __forceinline__ float bf16lo(unsigned int v) { return __uint_as_float(v << 16); }
__device__ __forceinline__ float bf16hi(unsigned int v) { return __uint_as_float(v & 0xffff0000u); }
__device__ __forceinline__ float bf16f(unsigned short v) { return __uint_as_float((unsigned int)v << 16); }

__device__ __forceinline__ void conv8(const float* __restrict__ src, unsigned short* __restrict__ dst, int i)
{
    float4 v0 = *reinterpret_cast<const float4*>(src + i);
    float4 v1 = *reinterpret_cast<const float4*>(src + i + 4);
    u16x8 o;
    o[0] = f_to_bf16(v0.x); o[1] = f_to_bf16(v0.y);
    o[2] = f_to_bf16(v0.z); o[3] = f_to_bf16(v0.w);
    o[4] = f_to_bf16(v1.x); o[5] = f_to_bf16(v1.y);
    o[6] = f_to_bf16(v1.z); o[7] = f_to_bf16(v1.w);
    *reinterpret_cast<u16x8*>(dst + i) = o;
}

__device__ __forceinline__ void acc_add(float* acc, uint4 v)
{
    acc[0] += bf16lo(v.x); acc[1] += bf16hi(v.x);
    acc[2] += bf16lo(v.y); acc[3] += bf16hi(v.y);
    acc[4] += bf16lo(v.z); acc[5] += bf16hi(v.z);
    acc[6] += bf16lo(v.w); acc[7] += bf16hi(v.w);
}

// ---------------------------------------------------------------------------
// Zero deg|cursor
// ---------------------------------------------------------------------------
__global__ __launch_bounds__(256) void zero_kernel(int* __restrict__ p, int n4)
{
    int i = blockIdx.x * 256 + threadIdx.x;
    if (i < n4) *reinterpret_cast<int4*>(p + i * 4) = make_int4(0, 0, 0, 0);
}

// ---------------------------------------------------------------------------
// Fused prep: conv_x | conv_w | hist, dispatched by block range.
// ---------------------------------------------------------------------------
__global__ __launch_bounds__(256) void prep_kernel(
    const float* __restrict__ x, unsigned short* __restrict__ xb,
    const float* __restrict__ w1l, const float* __restrict__ w1r,
    const float* __restrict__ w2l, const float* __restrict__ w2r,
    unsigned short* __restrict__ Wb,
    const int* __restrict__ dst, int* __restrict__ deg,
    int XB, int E)
{
    const int bx = blockIdx.x;
    if (bx < XB) {
        int i = (bx * 256 + threadIdx.x) * 8;
        if (i < N_NODES * D) conv8(x, xb, i);
    } else if (bx < XB + 24) {
        int i = ((bx - XB) * 256 + threadIdx.x) * 8;   // 49152 elems
        const float* src; int off;
        if      (i < 16384) { src = w1l; off = 0; }
        else if (i < 32768) { src = w1r; off = 16384; }
        else if (i < 40960) { src = w2l; off = 32768; }
        else                { src = w2r; off = 40960; }
        conv8(src, Wb + off, i - off);
    } else {
        int e = (bx - XB - 24) * 256 + threadIdx.x;
        if (e < E) atomicAdd(&deg[dst[e]], 1);
    }
}

// ---------------------------------------------------------------------------
// Scan step 1: per-block (1024 elems) local exclusive scan + block sums
// ---------------------------------------------------------------------------
__global__ __launch_bounds__(256) void scan1_kernel(
    const int* __restrict__ deg, int* __restrict__ part,
    int* __restrict__ bsum, int n)
{
    const int t = threadIdx.x;
    const int base = blockIdx.x * 1024 + t * 4;

    int a0 = 0, a1 = 0, a2 = 0, a3 = 0;
    if (base + 3 < n) {
        int4 v = *reinterpret_cast<const int4*>(deg + base);
        a0 = v.x; a1 = v.y; a2 = v.z; a3 = v.w;
    } else if (base < n) {
        a0 = deg[base];
        if (base + 1 < n) a1 = deg[base + 1];
        if (base + 2 < n) a2 = deg[base + 2];
    }
    const int s0 = a0, s1 = s0 + a1, s2 = s1 + a2, s3 = s2 + a3;

    const int lane = t & 63;
    int incl = s3;
#pragma unroll
    for (int off = 1; off < 64; off <<= 1) {
        int up = __shfl_up(incl, off);
        if (lane >= off) incl += up;
    }

    __shared__ int wsum[4];
    const int wid = t >> 6;
    if (lane == 63) wsum[wid] = incl;
    __syncthreads();

    int woff = 0;
#pragma unroll
    for (int w = 0; w < 4; ++w) woff += (w < wid) ? wsum[w] : 0;

    const int ex = woff + incl - s3;
    if (base + 3 < n) {
        int4 o; o.x = ex; o.y = ex + s0; o.z = ex + s1; o.w = ex + s2;
        *reinterpret_cast<int4*>(part + base) = o;
    } else if (base < n) {
        part[base] = ex;
        if (base + 1 < n) part[base + 1] = ex + s0;
        if (base + 2 < n) part[base + 2] = ex + s1;
    }
    if (t == 255) bsum[blockIdx.x] = woff + incl;
}

// ---------------------------------------------------------------------------
// Scan step 2: per-block offset from block sums (64-lane masked reduce),
// part + offset -> row_ptr; last block writes row_ptr[n].
// ---------------------------------------------------------------------------
__global__ __launch_bounds__(256) void scan3_kernel(
    const int* __restrict__ part, const int* __restrict__ bsum,
    int* __restrict__ row_ptr, int nb, int n)
{
    __shared__ int sAdd, sTot;
    const int t = threadIdx.x;
    const int bid = blockIdx.x;

    if (t < 64) {
        int v   = (t < nb) ? bsum[t] : 0;
        int add = (t < bid) ? v : 0;
        int tot = v;
#pragma unroll
        for (int off = 1; off < 64; off <<= 1) {
            add += __shfl_xor(add, off);
            tot += __shfl_xor(tot, off);
        }
        if (t == 0) { sAdd = add; sTot = tot; }
    }
    __syncthreads();

    const int add = sAdd;
    const int base = bid * 1024 + t * 4;
    if (base + 3 < n) {
        int4 v = *reinterpret_cast<const int4*>(part + base);
        v.x += add; v.y += add; v.z += add; v.w += add;
        *reinterpret_cast<int4*>(row_ptr + base) = v;
    } else if (base < n) {
        row_ptr[base] = part[base] + add;
        if (base + 1 < n) row_ptr[base + 1] = part[base + 1] + add;
        if (base + 2 < n) row_ptr[base + 2] = part[base + 2] + add;
    }
    if (bid == nb - 1 && t == 0) row_ptr[n] = sTot;
}

// ---------------------------------------------------------------------------
// CSR bucket-fill
// ---------------------------------------------------------------------------
__global__ __launch_bounds__(256) void fill_kernel(
    const int* __restrict__ src, const int* __restrict__ dst,
    const int* __restrict__ row_ptr, int* __restrict__ cursor,
    int* __restrict__ esrc, int E)
{
    int e = blockIdx.x * blockDim.x + threadIdx.x;
    if (e >= E) return;
    int d = dst[e];
    int pos = atomicAdd(&cursor[d], 1);
    esrc[row_ptr[d] + pos] = src[e];
}

// ---------------------------------------------------------------------------
// Gather-aggregate (bf16), 1 wave/node (4 waves/block), predicated loads.
//   CHUNKS=16 (256B rows): RPL=4,  NLOADS=8 -> 32 rows/iter
//   CHUNKS=8  (128B rows): RPL=8,  NLOADS=8 -> 64 rows/iter
// ---------------------------------------------------------------------------
template<int CHUNKS>
__global__ __launch_bounds__(256) void gather_bf16_kernel(
    const unsigned short* __restrict__ xb,
    const int* __restrict__ row_ptr,
    const int* __restrict__ esrc,
    unsigned short* __restrict__ aggb,
    int n_nodes)
{
    constexpr int RPL = 64 / CHUNKS;        // rows per load instr
    constexpr int NLOADS = 8;               // predicated loads per iter
    constexpr int ITER = RPL * NLOADS;      // rows per iteration
    const int wv   = threadIdx.x >> 6;
    const int lane = threadIdx.x & 63;
    const int node = blockIdx.x * 4 + wv;
    if (node >= n_nodes) return;

    const int beg = row_ptr[node];
    const int end = row_ptr[node + 1];
    const int g = lane / CHUNKS;            // row slot within load
    const int c = lane % CHUNKS;            // 16B column chunk

    const uint4* x4 = reinterpret_cast<const uint4*>(xb);

    float acc[8];
#pragma unroll
    for (int k = 0; k < 8; ++k) acc[k] = 0.f;

    for (int base = beg; base < end; base += 64) {
        const int cnt = min(end - base, 64);
        int s = (base + lane < end) ? esrc[base + lane] : 0;
        for (int i = 0; i < cnt; i += ITER) {
            int pp[NLOADS]; uint4 vv[NLOADS]; bool ok[NLOADS];
#pragma unroll
            for (int j = 0; j < NLOADS; ++j) {
                pp[j] = i + j * RPL + g;
                int sj = __shfl(s, pp[j] & 63);
                ok[j] = pp[j] < cnt;
                if (ok[j]) vv[j] = x4[(size_t)sj * CHUNKS + c];
            }
#pragma unroll
            for (int j = 0; j < NLOADS; ++j)
                if (ok[j]) acc_add(acc, vv[j]);
        }
    }

    // combine row-slot groups (lanes sharing chunk c)
#pragma unroll
    for (int k = 0; k < 8; ++k) {
#pragma unroll
        for (int off = CHUNKS; off < 64; off <<= 1)
            acc[k] += __shfl_xor(acc[k], off);
    }

    if (g == 0) {
        const float inv = (end > beg) ? 1.0f / (float)(end - beg) : 0.0f;
        uint4 o;
        o.x = (unsigned int)f_to_bf16(acc[0] * inv) | ((unsigned int)f_to_bf16(acc[1] * inv) << 16);
        o.y = (unsigned int)f_to_bf16(acc[2] * inv) | ((unsigned int)f_to_bf16(acc[3] * inv) << 16);
        o.z = (unsigned int)f_to_bf16(acc[4] * inv) | ((unsigned int)f_to_bf16(acc[5] * inv) << 16);
        o.w = (unsigned int)f_to_bf16(acc[6] * inv) | ((unsigned int)f_to_bf16(acc[7] * inv) << 16);
        reinterpret_cast<uint4*>(aggb)[(size_t)node * CHUNKS + c] = o;
    }
}

// ---------------------------------------------------------------------------
// Layer 1 via MFMA 16x16x32 bf16 — 4 tiles per 256-thread block (wave wv owns
// tile blockIdx*4+wv; 4 waves share L1 for the W stream; no cross-wave LDS).
// Emits t2 = h1 · W2l^T ([N,64] bf16): linearity mean(h1)·Wl = mean(h1·Wl).
// D-layout: col = lane&15, row = (lane>>4)*4 + reg   [m89 verified]
// ---------------------------------------------------------------------------
__global__ __launch_bounds__(256) void layer1_mfma_kernel(
    const unsigned short* __restrict__ aggb,
    const unsigned short* __restrict__ xb,
    const unsigned short* __restrict__ Wb,   // W1l@0, W1r@16384, W2l@32768
    const float* __restrict__ b1,
    unsigned short* __restrict__ h1b,
    unsigned short* __restrict__ t2b,        // [N,64]
    int n_tiles)
{
    __shared__ unsigned short h1s[4][16][144];  // per-wave slice, 16B-aligned rows

    const int wv    = threadIdx.x >> 6;
    const int lane  = threadIdx.x & 63;
    const int tile  = blockIdx.x * 4 + wv;
    if (tile >= n_tiles) return;
    const int node0 = tile * 16;
    const int c16   = lane & 15;
    const int kg    = lane >> 4;

    bf16x8 a[2][4];
    {
        const unsigned short* A0 = aggb + (size_t)(node0 + c16) * D + kg * 8;
        const unsigned short* A1 = xb   + (size_t)(node0 + c16) * D + kg * 8;
#pragma unroll
        for (int kf = 0; kf < 4; ++kf) {
            a[0][kf] = *reinterpret_cast<const bf16x8*>(A0 + kf * 32);
            a[1][kf] = *reinterpret_cast<const bf16x8*>(A1 + kf * 32);
        }
    }
    const unsigned short* WL = Wb;
    const unsigned short* WR = Wb + 16384;

#pragma unroll 2
    for (int jt = 0; jt < 8; ++jt) {
        f32x4 acc = {0.f, 0.f, 0.f, 0.f};
        const unsigned short* wl = WL + (size_t)(jt * 16 + c16) * D + kg * 8;
        const unsigned short* wr = WR + (size_t)(jt * 16 + c16) * D + kg * 8;
#pragma unroll
        for (int kf = 0; kf < 4; ++kf) {
            bf16x8 b = *reinterpret_cast<const bf16x8*>(wl + kf * 32);
            acc = __builtin_amdgcn_mfma_f32_16x16x32_bf16(a[0][kf], b, acc, 0, 0, 0);
        }
#pragma unroll
        for (int kf = 0; kf < 4; ++kf) {
            bf16x8 b = *reinterpret_cast<const bf16x8*>(wr + kf * 32);
            acc = __builtin_amdgcn_mfma_f32_16x16x32_bf16(a[1][kf], b, acc, 0, 0, 0);
        }
        const float bias = b1[jt * 16 + c16];
#pragma unroll
        for (int i = 0; i < 4; ++i) {
            float v = fmaxf(acc[i] + bias, 0.0f);
            unsigned short us = f_to_bf16(v);
            h1b[(size_t)(node0 + kg * 4 + i) * D + jt * 16 + c16] = us;
            h1s[wv][kg * 4 + i][jt * 16 + c16] = us;
        }
    }

    // t2 = h1_tile (16x128) · W2l^T -> 16x64  (per-wave LDS slice; within-wave
    // ds_write -> ds_read ordering is handled by compiler-inserted lgkmcnt)
    bf16x8 a2[4];
#pragma unroll
    for (int kf = 0; kf < 4; ++kf)
        a2[kf] = *reinterpret_cast<const bf16x8*>(&h1s[wv][c16][kg * 8 + kf * 32]);

    const unsigned short* W2L = Wb + 32768;
#pragma unroll
    for (int jt = 0; jt < 4; ++jt) {
        f32x4 acc = {0.f, 0.f, 0.f, 0.f};
        const unsigned short* wl = W2L + (size_t)(jt * 16 + c16) * D + kg * 8;
#pragma unroll
        for (int kf = 0; kf < 4; ++kf) {
            bf16x8 b = *reinterpret_cast<const bf16x8*>(wl + kf * 32);
            acc = __builtin_amdgcn_mfma_f32_16x16x32_bf16(a2[kf], b, acc, 0, 0, 0);
        }
#pragma unroll
        for (int i = 0; i < 4; ++i)
            t2b[(size_t)(node0 + kg * 4 + i) * D_OUT + jt * 16 + c16] = f_to_bf16(acc[i]);
    }
}

// ---------------------------------------------------------------------------
// Layer 2: out = log_softmax( agg(t2) + b2 + h1·W2r^T ) — 4 tiles per block.
// ---------------------------------------------------------------------------
__global__ __launch_bounds__(256) void layer2_mfma_kernel(
    const unsigned short* __restrict__ agg2b,   // [N,64] premeaned t2
    const unsigned short* __restrict__ h1b,
    const unsigned short* __restrict__ Wb,      // W2r@40960
    const float* __restrict__ b2,
    float* __restrict__ out,
    int n_tiles)
{
    const int wv    = threadIdx.x >> 6;
    const int lane  = threadIdx.x & 63;
    const int tile  = blockIdx.x * 4 + wv;
    if (tile >= n_tiles) return;
    const int node0 = tile * 16;
    const int c16   = lane & 15;
    const int kg    = lane >> 4;

    bf16x8 a[4];
    {
        const unsigned short* A1 = h1b + (size_t)(node0 + c16) * D + kg * 8;
#pragma unroll
        for (int kf = 0; kf < 4; ++kf)
            a[kf] = *reinterpret_cast<const bf16x8*>(A1 + kf * 32);
    }
    const unsigned short* WR = Wb + 40960;

    f32x4 accs[4];
#pragma unroll
    for (int jt = 0; jt < 4; ++jt) {
        f32x4 acc = {0.f, 0.f, 0.f, 0.f};
        const unsigned short* wr = WR + (size_t)(jt * 16 + c16) * D + kg * 8;
#pragma unroll
        for (int kf = 0; kf < 4; ++kf) {
            bf16x8 b = *reinterpret_cast<const bf16x8*>(wr + kf * 32);
            acc = __builtin_amdgcn_mfma_f32_16x16x32_bf16(a[kf], b, acc, 0, 0, 0);
        }
        accs[jt] = acc;
    }

    float bias[4];
#pragma unroll
    for (int jt = 0; jt < 4; ++jt) bias[jt] = b2[jt * 16 + c16];

#pragma unroll
    for (int i = 0; i < 4; ++i) {
        const int node = node0 + kg * 4 + i;
        float z[4];
        float m = -1e30f;
#pragma unroll
        for (int jt = 0; jt < 4; ++jt) {
            float lft = bf16f(agg2b[(size_t)node * D_OUT + jt * 16 + c16]);
            z[jt] = lft + accs[jt][i] + bias[jt];
            m = fmaxf(m, z[jt]);
        }
#pragma unroll
        for (int off = 1; off < 16; off <<= 1)
            m = fmaxf(m, __shfl_xor(m, off));
        float s = 0.f;
#pragma unroll
        for (int jt = 0; jt < 4; ++jt) s += expf(z[jt] - m);
#pragma unroll
        for (int off = 1; off < 16; off <<= 1)
            s += __shfl_xor(s, off);
        float lse = m + logf(s);
#pragma unroll
        for (int jt = 0; jt < 4; ++jt)
            out[(size_t)node * D_OUT + jt * 16 + c16] = z[jt] - lse;
    }
}

// ---------------------------------------------------------------------------
extern "C" void kernel_launch(void* const* d_in, const int* in_sizes, int n_in,
                              void* d_out, int out_size, void* d_ws, size_t ws_size,
                              hipStream_t stream)
{
    const float* x   = (const float*)d_in[0];
    const int*   ei  = (const int*)d_in[1];
    const float* W1l = (const float*)d_in[2];
    const float* b1  = (const float*)d_in[3];
    const float* W1r = (const float*)d_in[4];
    const float* W2l = (const float*)d_in[5];
    const float* b2  = (const float*)d_in[6];
    const float* W2r = (const float*)d_in[7];
    float* out = (float*)d_out;

    const int E = in_sizes[1] / 2;
    const int* src = ei;
    const int* dst = ei + E;

    // ---- workspace layout (256B-aligned chunks) ----
    char* base = (char*)d_ws;
    size_t off = 0;
    auto take = [&](size_t bytes) { char* p = base + off; off += (bytes + 255) & ~(size_t)255; return p; };

    unsigned short* xb    = (unsigned short*)take((size_t)N_NODES * D * 2);
    unsigned short* aggb  = (unsigned short*)take((size_t)N_NODES * D * 2);
    unsigned short* h1b   = (unsigned short*)take((size_t)N_NODES * D * 2);
    unsigned short* t2b   = (unsigned short*)take((size_t)N_NODES * D_OUT * 2);
    unsigned short* agg2b = (unsigned short*)take((size_t)N_NODES * D_OUT * 2);
    unsigned short* Wb    = (unsigned short*)take((size_t)49152 * 2);
    int* degcur  = (int*)take((size_t)2 * N_NODES * 4);   // deg | cursor
    int* deg     = degcur;
    int* cursor  = degcur + N_NODES;
    int* row_ptr = (int*)take(((size_t)N_NODES + 1) * 4);
    int* part    = (int*)take((size_t)N_NODES * 4);
    int* bsum    = (int*)take((size_t)64 * 4);
    int* esrc    = (int*)take((size_t)E * 4);

    const int EB = (E + 255) / 256;
    const int SB = (N_NODES + 1023) / 1024;       // 49 scan blocks
    const int XB = (N_NODES * D / 8 + 255) / 256; // 3125 conv_x blocks
    const int GB = (N_NODES + 3) / 4;             // gather: 4 nodes per block
    const int NT = N_NODES / 16;                  // 3125 MFMA tiles, exact
    const int LB = (NT + 3) / 4;                  // 782 layer blocks (4 tiles each)

    zero_kernel<<<(2 * N_NODES / 4 + 255) / 256, 256, 0, stream>>>(degcur, 2 * N_NODES / 4);
    prep_kernel<<<XB + 24 + EB, 256, 0, stream>>>(x, xb, W1l, W1r, W2l, W2r, Wb, dst, deg, XB, E);
    scan1_kernel<<<SB, 256, 0, stream>>>(deg, part, bsum, N_NODES);
    scan3_kernel<<<SB, 256, 0, stream>>>(part, bsum, row_ptr, SB, N_NODES);
    fill_kernel<<<EB, 256, 0, stream>>>(src, dst, row_ptr, cursor, esrc, E);

    // ---- layer 1 (+ t2 = h1·W2l^T) ----
    gather_bf16_kernel<16><<<GB, 256, 0, stream>>>(xb, row_ptr, esrc, aggb, N_NODES);
    layer1_mfma_kernel<<<LB, 256, 0, stream>>>(aggb, xb, Wb, b1, h1b, t2b, NT);

    // ---- layer 2 (gather over 128B t2 rows) ----
    gather_bf16_kernel<8><<<GB, 256, 0, stream>>>(t2b, row_ptr, esrc, agg2b, N_NODES);
    layer2_mfma_kernel<<<LB, 256, 0, stream>>>(agg2b, h1b, Wb, b2, out, NT);
}

// Round 16
// 161.072 us; speedup vs baseline: 1.2129x; 1.1003x over previous
//
#include <hip/hip_runtime.h>
#include <math.h>

#define N_NODES 50000
#define D 128       // d_in == d_hid
#define D_OUT 64

typedef short bf16x8 __attribute__((ext_vector_type(8)));   // 8 bf16 (4 VGPR) MFMA frag
typedef float f32x4  __attribute__((ext_vector_type(4)));   // MFMA accumulator
typedef unsigned short u16x8 __attribute__((ext_vector_type(8)));

__device__ __forceinline__ unsigned short f_to_bf16(float f) {
    unsigned int u = __float_as_uint(f);
    u = (u + 0x7fffu + ((u >> 16) & 1u)) >> 16;   // RNE
    return (unsigned short)u;
}
__device__ __forceinline__ float bf16lo(unsigned int v) { return __uint_as_float(v << 16); }
__device__ __forceinline__ float bf16hi(unsigned int v) { return __uint_as_float(v & 0xffff0000u); }
__device__ __forceinline__ float bf16f(unsigned short v) { return __uint_as_float((unsigned int)v << 16); }

__device__ __forceinline__ void conv8(const float* __restrict__ src, unsigned short* __restrict__ dst, int i)
{
    float4 v0 = *reinterpret_cast<const float4*>(src + i);
    float4 v1 = *reinterpret_cast<const float4*>(src + i + 4);
    u16x8 o;
    o[0] = f_to_bf16(v0.x); o[1] = f_to_bf16(v0.y);
    o[2] = f_to_bf16(v0.z); o[3] = f_to_bf16(v0.w);
    o[4] = f_to_bf16(v1.x); o[5] = f_to_bf16(v1.y);
    o[6] = f_to_bf16(v1.z); o[7] = f_to_bf16(v1.w);
    *reinterpret_cast<u16x8*>(dst + i) = o;
}

__device__ __forceinline__ void acc_add(float* acc, uint4 v)
{
    acc[0] += bf16lo(v.x); acc[1] += bf16hi(v.x);
    acc[2] += bf16lo(v.y); acc[3] += bf16hi(v.y);
    acc[4] += bf16lo(v.z); acc[5] += bf16hi(v.z);
    acc[6] += bf16lo(v.w); acc[7] += bf16hi(v.w);
}

// ---------------------------------------------------------------------------
// Zero deg|cursor
// ---------------------------------------------------------------------------
__global__ __launch_bounds__(256) void zero_kernel(int* __restrict__ p, int n4)
{
    int i = blockIdx.x * 256 + threadIdx.x;
    if (i < n4) *reinterpret_cast<int4*>(p + i * 4) = make_int4(0, 0, 0, 0);
}

// ---------------------------------------------------------------------------
// Fused prep: conv_x | conv_w | hist, dispatched by block range.
// ---------------------------------------------------------------------------
__global__ __launch_bounds__(256) void prep_kernel(
    const float* __restrict__ x, unsigned short* __restrict__ xb,
    const float* __restrict__ w1l, const float* __restrict__ w1r,
    const float* __restrict__ w2l, const float* __restrict__ w2r,
    unsigned short* __restrict__ Wb,
    const int* __restrict__ dst, int* __restrict__ deg,
    int XB, int E)
{
    const int bx = blockIdx.x;
    if (bx < XB) {
        int i = (bx * 256 + threadIdx.x) * 8;
        if (i < N_NODES * D) conv8(x, xb, i);
    } else if (bx < XB + 24) {
        int i = ((bx - XB) * 256 + threadIdx.x) * 8;   // 49152 elems
        const float* src; int off;
        if      (i < 16384) { src = w1l; off = 0; }
        else if (i < 32768) { src = w1r; off = 16384; }
        else if (i < 40960) { src = w2l; off = 32768; }
        else                { src = w2r; off = 40960; }
        conv8(src, Wb + off, i - off);
    } else {
        int e = (bx - XB - 24) * 256 + threadIdx.x;
        if (e < E) atomicAdd(&deg[dst[e]], 1);
    }
}

// ---------------------------------------------------------------------------
// Scan step 1: per-block (1024 elems) local exclusive scan + block sums
// ---------------------------------------------------------------------------
__global__ __launch_bounds__(256) void scan1_kernel(
    const int* __restrict__ deg, int* __restrict__ part,
    int* __restrict__ bsum, int n)
{
    const int t = threadIdx.x;
    const int base = blockIdx.x * 1024 + t * 4;

    int a0 = 0, a1 = 0, a2 = 0, a3 = 0;
    if (base + 3 < n) {
        int4 v = *reinterpret_cast<const int4*>(deg + base);
        a0 = v.x; a1 = v.y; a2 = v.z; a3 = v.w;
    } else if (base < n) {
        a0 = deg[base];
        if (base + 1 < n) a1 = deg[base + 1];
        if (base + 2 < n) a2 = deg[base + 2];
    }
    const int s0 = a0, s1 = s0 + a1, s2 = s1 + a2, s3 = s2 + a3;

    const int lane = t & 63;
    int incl = s3;
#pragma unroll
    for (int off = 1; off < 64; off <<= 1) {
        int up = __shfl_up(incl, off);
        if (lane >= off) incl += up;
    }

    __shared__ int wsum[4];
    const int wid = t >> 6;
    if (lane == 63) wsum[wid] = incl;
    __syncthreads();

    int woff = 0;
#pragma unroll
    for (int w = 0; w < 4; ++w) woff += (w < wid) ? wsum[w] : 0;

    const int ex = woff + incl - s3;
    if (base + 3 < n) {
        int4 o; o.x = ex; o.y = ex + s0; o.z = ex + s1; o.w = ex + s2;
        *reinterpret_cast<int4*>(part + base) = o;
    } else if (base < n) {
        part[base] = ex;
        if (base + 1 < n) part[base + 1] = ex + s0;
        if (base + 2 < n) part[base + 2] = ex + s1;
    }
    if (t == 255) bsum[blockIdx.x] = woff + incl;
}

// ---------------------------------------------------------------------------
// Scan step 2: per-block offset from block sums (64-lane masked reduce),
// part + offset -> row_ptr; last block writes row_ptr[n].
// ---------------------------------------------------------------------------
__global__ __launch_bounds__(256) void scan3_kernel(
    const int* __restrict__ part, const int* __restrict__ bsum,
    int* __restrict__ row_ptr, int nb, int n)
{
    __shared__ int sAdd, sTot;
    const int t = threadIdx.x;
    const int bid = blockIdx.x;

    if (t < 64) {
        int v   = (t < nb) ? bsum[t] : 0;
        int add = (t < bid) ? v : 0;
        int tot = v;
#pragma unroll
        for (int off = 1; off < 64; off <<= 1) {
            add += __shfl_xor(add, off);
            tot += __shfl_xor(tot, off);
        }
        if (t == 0) { sAdd = add; sTot = tot; }
    }
    __syncthreads();

    const int add = sAdd;
    const int base = bid * 1024 + t * 4;
    if (base + 3 < n) {
        int4 v = *reinterpret_cast<const int4*>(part + base);
        v.x += add; v.y += add; v.z += add; v.w += add;
        *reinterpret_cast<int4*>(row_ptr + base) = v;
    } else if (base < n) {
        row_ptr[base] = part[base] + add;
        if (base + 1 < n) row_ptr[base + 1] = part[base + 1] + add;
        if (base + 2 < n) row_ptr[base + 2] = part[base + 2] + add;
    }
    if (bid == nb - 1 && t == 0) row_ptr[n] = sTot;
}

// ---------------------------------------------------------------------------
// CSR bucket-fill
// ---------------------------------------------------------------------------
__global__ __launch_bounds__(256) void fill_kernel(
    const int* __restrict__ src, const int* __restrict__ dst,
    const int* __restrict__ row_ptr, int* __restrict__ cursor,
    int* __restrict__ esrc, int E)
{
    int e = blockIdx.x * blockDim.x + threadIdx.x;
    if (e >= E) return;
    int d = dst[e];
    int pos = atomicAdd(&cursor[d], 1);
    esrc[row_ptr[d] + pos] = src[e];
}

// ---------------------------------------------------------------------------
// Gather-aggregate (bf16), 1 wave/node (4 waves/block), predicated loads.
// (unchanged from round 13 — best measured config)
// ---------------------------------------------------------------------------
template<int CHUNKS>
__global__ __launch_bounds__(256) void gather_bf16_kernel(
    const unsigned short* __restrict__ xb,
    const int* __restrict__ row_ptr,
    const int* __restrict__ esrc,
    unsigned short* __restrict__ aggb,
    int n_nodes)
{
    constexpr int RPL = 64 / CHUNKS;        // rows per load instr
    constexpr int NLOADS = 8;               // predicated loads per iter
    constexpr int ITER = RPL * NLOADS;      // rows per iteration
    const int wv   = threadIdx.x >> 6;
    const int lane = threadIdx.x & 63;
    const int node = blockIdx.x * 4 + wv;
    if (node >= n_nodes) return;

    const int beg = row_ptr[node];
    const int end = row_ptr[node + 1];
    const int g = lane / CHUNKS;            // row slot within load
    const int c = lane % CHUNKS;            // 16B column chunk

    const uint4* x4 = reinterpret_cast<const uint4*>(xb);

    float acc[8];
#pragma unroll
    for (int k = 0; k < 8; ++k) acc[k] = 0.f;

    for (int base = beg; base < end; base += 64) {
        const int cnt = min(end - base, 64);
        int s = (base + lane < end) ? esrc[base + lane] : 0;
        for (int i = 0; i < cnt; i += ITER) {
            int pp[NLOADS]; uint4 vv[NLOADS]; bool ok[NLOADS];
#pragma unroll
            for (int j = 0; j < NLOADS; ++j) {
                pp[j] = i + j * RPL + g;
                int sj = __shfl(s, pp[j] & 63);
                ok[j] = pp[j] < cnt;
                if (ok[j]) vv[j] = x4[(size_t)sj * CHUNKS + c];
            }
#pragma unroll
            for (int j = 0; j < NLOADS; ++j)
                if (ok[j]) acc_add(acc, vv[j]);
        }
    }

#pragma unroll
    for (int k = 0; k < 8; ++k) {
#pragma unroll
        for (int off = CHUNKS; off < 64; off <<= 1)
            acc[k] += __shfl_xor(acc[k], off);
    }

    if (g == 0) {
        const float inv = (end > beg) ? 1.0f / (float)(end - beg) : 0.0f;
        uint4 o;
        o.x = (unsigned int)f_to_bf16(acc[0] * inv) | ((unsigned int)f_to_bf16(acc[1] * inv) << 16);
        o.y = (unsigned int)f_to_bf16(acc[2] * inv) | ((unsigned int)f_to_bf16(acc[3] * inv) << 16);
        o.z = (unsigned int)f_to_bf16(acc[4] * inv) | ((unsigned int)f_to_bf16(acc[5] * inv) << 16);
        o.w = (unsigned int)f_to_bf16(acc[6] * inv) | ((unsigned int)f_to_bf16(acc[7] * inv) << 16);
        reinterpret_cast<uint4*>(aggb)[(size_t)node * CHUNKS + c] = o;
    }
}

// ---------------------------------------------------------------------------
// Layer 1 — W-amortized: block = 4 waves = 64 nodes (4 MFMA tiles).
// Stage agg+x rows in LDS once; wave wv owns jt ∈ {wv, wv+4}: W-frags loaded
// ONCE per jt (registers), MFMA'd against all 4 tiles from LDS.
// W-load batches/wave: 12 -> 3; MFMA per batch: 8 -> 32.
// Then t2 = h1·W2l^T via LDS h1 tile (wave wv does jt=wv).
// D-layout: col = lane&15, row = (lane>>4)*4 + reg   [m89 verified]
// ---------------------------------------------------------------------------
__global__ __launch_bounds__(256) void layer1_mfma_kernel(
    const unsigned short* __restrict__ aggb,
    const unsigned short* __restrict__ xb,
    const unsigned short* __restrict__ Wb,   // W1l@0, W1r@16384, W2l@32768
    const float* __restrict__ b1,
    unsigned short* __restrict__ h1b,
    unsigned short* __restrict__ t2b,        // [N,64]
    int n_tiles)
{
    __shared__ unsigned short As[64][136];   // agg rows (272B stride: 2-way alias, free)
    __shared__ unsigned short Xs[64][136];   // x rows
    __shared__ unsigned short Hs[64][136];   // h1 tile (for t2)

    const int tid  = threadIdx.x;
    const int wv   = tid >> 6, lane = tid & 63;
    const int tile0 = blockIdx.x * 4;
    const int node0 = tile0 * 16;

    // ---- stage 64 agg rows + 64 x rows (coalesced, guarded) ----
    for (int q = tid; q < 1024; q += 256) {
        const int row = q >> 4, c = q & 15;
        const int node = node0 + row;
        uint4 va = make_uint4(0, 0, 0, 0), vx = va;
        if (node < N_NODES) {
            va = reinterpret_cast<const uint4*>(aggb)[(size_t)node * 16 + c];
            vx = reinterpret_cast<const uint4*>(xb)  [(size_t)node * 16 + c];
        }
        *reinterpret_cast<uint4*>(&As[row][c * 8]) = va;
        *reinterpret_cast<uint4*>(&Xs[row][c * 8]) = vx;
    }
    __syncthreads();

    const int c16 = lane & 15, kg = lane >> 4;

    // ---- main: wave wv computes jt = wv and wv+4 for all 4 tiles ----
#pragma unroll
    for (int jj = 0; jj < 2; ++jj) {
        const int jt = wv + jj * 4;
        bf16x8 wlf[4], wrf[4];
        {
            const unsigned short* wl = Wb +         (size_t)(jt * 16 + c16) * D + kg * 8;
            const unsigned short* wr = Wb + 16384 + (size_t)(jt * 16 + c16) * D + kg * 8;
#pragma unroll
            for (int kf = 0; kf < 4; ++kf) {
                wlf[kf] = *reinterpret_cast<const bf16x8*>(wl + kf * 32);
                wrf[kf] = *reinterpret_cast<const bf16x8*>(wr + kf * 32);
            }
        }
        const float bias = b1[jt * 16 + c16];

#pragma unroll
        for (int t = 0; t < 4; ++t) {
            if (tile0 + t < n_tiles) {
                const int r0 = t * 16;
                f32x4 acc = {0.f, 0.f, 0.f, 0.f};
#pragma unroll
                for (int kf = 0; kf < 4; ++kf) {
                    bf16x8 a0 = *reinterpret_cast<const bf16x8*>(&As[r0 + c16][kg * 8 + kf * 32]);
                    acc = __builtin_amdgcn_mfma_f32_16x16x32_bf16(a0, wlf[kf], acc, 0, 0, 0);
                }
#pragma unroll
                for (int kf = 0; kf < 4; ++kf) {
                    bf16x8 a1 = *reinterpret_cast<const bf16x8*>(&Xs[r0 + c16][kg * 8 + kf * 32]);
                    acc = __builtin_amdgcn_mfma_f32_16x16x32_bf16(a1, wrf[kf], acc, 0, 0, 0);
                }
#pragma unroll
                for (int i = 0; i < 4; ++i) {
                    const int row = r0 + kg * 4 + i;
                    float v = fmaxf(acc[i] + bias, 0.0f);
                    unsigned short us = f_to_bf16(v);
                    h1b[(size_t)(node0 + row) * D + jt * 16 + c16] = us;
                    Hs[row][jt * 16 + c16] = us;
                }
            }
        }
    }
    __syncthreads();

    // ---- t2: wave wv computes jt = wv for all 4 tiles ----
    {
        const int jt = wv;
        bf16x8 w2f[4];
        {
            const unsigned short* wl = Wb + 32768 + (size_t)(jt * 16 + c16) * D + kg * 8;
#pragma unroll
            for (int kf = 0; kf < 4; ++kf)
                w2f[kf] = *reinterpret_cast<const bf16x8*>(wl + kf * 32);
        }
#pragma unroll
        for (int t = 0; t < 4; ++t) {
            if (tile0 + t < n_tiles) {
                const int r0 = t * 16;
                f32x4 acc = {0.f, 0.f, 0.f, 0.f};
#pragma unroll
                for (int kf = 0; kf < 4; ++kf) {
                    bf16x8 a2 = *reinterpret_cast<const bf16x8*>(&Hs[r0 + c16][kg * 8 + kf * 32]);
                    acc = __builtin_amdgcn_mfma_f32_16x16x32_bf16(a2, w2f[kf], acc, 0, 0, 0);
                }
#pragma unroll
                for (int i = 0; i < 4; ++i)
                    t2b[(size_t)(node0 + r0 + kg * 4 + i) * D_OUT + jt * 16 + c16] = f_to_bf16(acc[i]);
            }
        }
    }
}

// ---------------------------------------------------------------------------
// Layer 2 — W-amortized: block = 4 waves = 64 nodes; wave wv owns jt = wv
// (4 W-frags loaded once), streams h1 frags from global (one read each),
// z staged in LDS, per-wave softmax over 16 rows.
// ---------------------------------------------------------------------------
__global__ __launch_bounds__(256) void layer2_mfma_kernel(
    const unsigned short* __restrict__ agg2b,   // [N,64] premeaned t2
    const unsigned short* __restrict__ h1b,
    const unsigned short* __restrict__ Wb,      // W2r@40960
    const float* __restrict__ b2,
    float* __restrict__ out,
    int n_tiles)
{
    __shared__ float zs[64][68];   // 272B stride

    const int tid  = threadIdx.x;
    const int wv   = tid >> 6, lane = tid & 63;
    const int tile0 = blockIdx.x * 4;
    const int node0 = tile0 * 16;
    const int c16 = lane & 15, kg = lane >> 4;

    const int jt = wv;
    bf16x8 wf[4];
    {
        const unsigned short* wr = Wb + 40960 + (size_t)(jt * 16 + c16) * D + kg * 8;
#pragma unroll
        for (int kf = 0; kf < 4; ++kf)
            wf[kf] = *reinterpret_cast<const bf16x8*>(wr + kf * 32);
    }
    const float bias = b2[jt * 16 + c16];

#pragma unroll
    for (int t = 0; t < 4; ++t) {
        if (tile0 + t < n_tiles) {
            const int r0 = t * 16;
            f32x4 acc = {0.f, 0.f, 0.f, 0.f};
            const unsigned short* A1 = h1b + (size_t)(node0 + r0 + c16) * D + kg * 8;
#pragma unroll
            for (int kf = 0; kf < 4; ++kf) {
                bf16x8 a = *reinterpret_cast<const bf16x8*>(A1 + kf * 32);
                acc = __builtin_amdgcn_mfma_f32_16x16x32_bf16(a, wf[kf], acc, 0, 0, 0);
            }
#pragma unroll
            for (int i = 0; i < 4; ++i) {
                const int row = r0 + kg * 4 + i;
                float lft = bf16f(agg2b[(size_t)(node0 + row) * D_OUT + jt * 16 + c16]);
                zs[row][jt * 16 + c16] = lft + acc[i] + bias;
            }
        }
    }
    __syncthreads();

    // softmax: wave wv handles rows [wv*16, wv*16+16)
    for (int r = 0; r < 16; ++r) {
        const int row = wv * 16 + r;
        if (tile0 + (row >> 4) >= n_tiles) break;
        float z = zs[row][lane];
        float m = z;
#pragma unroll
        for (int off = 1; off < 64; off <<= 1)
            m = fmaxf(m, __shfl_xor(m, off));
        float e = expf(z - m);
        float s = e;
#pragma unroll
        for (int off = 1; off < 64; off <<= 1)
            s += __shfl_xor(s, off);
        out[(size_t)(node0 + row) * D_OUT + lane] = z - m - logf(s);
    }
}

// ---------------------------------------------------------------------------
extern "C" void kernel_launch(void* const* d_in, const int* in_sizes, int n_in,
                              void* d_out, int out_size, void* d_ws, size_t ws_size,
                              hipStream_t stream)
{
    const float* x   = (const float*)d_in[0];
    const int*   ei  = (const int*)d_in[1];
    const float* W1l = (const float*)d_in[2];
    const float* b1  = (const float*)d_in[3];
    const float* W1r = (const float*)d_in[4];
    const float* W2l = (const float*)d_in[5];
    const float* b2  = (const float*)d_in[6];
    const float* W2r = (const float*)d_in[7];
    float* out = (float*)d_out;

    const int E = in_sizes[1] / 2;
    const int* src = ei;
    const int* dst = ei + E;

    // ---- workspace layout (256B-aligned chunks) ----
    char* base = (char*)d_ws;
    size_t off = 0;
    auto take = [&](size_t bytes) { char* p = base + off; off += (bytes + 255) & ~(size_t)255; return p; };

    unsigned short* xb    = (unsigned short*)take((size_t)N_NODES * D * 2);
    unsigned short* aggb  = (unsigned short*)take((size_t)N_NODES * D * 2);
    unsigned short* h1b   = (unsigned short*)take((size_t)N_NODES * D * 2);
    unsigned short* t2b   = (unsigned short*)take((size_t)N_NODES * D_OUT * 2);
    unsigned short* agg2b = (unsigned short*)take((size_t)N_NODES * D_OUT * 2);
    unsigned short* Wb    = (unsigned short*)take((size_t)49152 * 2);
    int* degcur  = (int*)take((size_t)2 * N_NODES * 4);   // deg | cursor
    int* deg     = degcur;
    int* cursor  = degcur + N_NODES;
    int* row_ptr = (int*)take(((size_t)N_NODES + 1) * 4);
    int* part    = (int*)take((size_t)N_NODES * 4);
    int* bsum    = (int*)take((size_t)64 * 4);
    int* esrc    = (int*)take((size_t)E * 4);

    const int EB = (E + 255) / 256;
    const int SB = (N_NODES + 1023) / 1024;       // 49 scan blocks
    const int XB = (N_NODES * D / 8 + 255) / 256; // 3125 conv_x blocks
    const int GB = (N_NODES + 3) / 4;             // gather: 4 nodes per block
    const int NT = N_NODES / 16;                  // 3125 MFMA tiles, exact
    const int LB = (NT + 3) / 4;                  // 782 layer blocks (64 nodes each)

    zero_kernel<<<(2 * N_NODES / 4 + 255) / 256, 256, 0, stream>>>(degcur, 2 * N_NODES / 4);
    prep_kernel<<<XB + 24 + EB, 256, 0, stream>>>(x, xb, W1l, W1r, W2l, W2r, Wb, dst, deg, XB, E);
    scan1_kernel<<<SB, 256, 0, stream>>>(deg, part, bsum, N_NODES);
    scan3_kernel<<<SB, 256, 0, stream>>>(part, bsum, row_ptr, SB, N_NODES);
    fill_kernel<<<EB, 256, 0, stream>>>(src, dst, row_ptr, cursor, esrc, E);

    // ---- layer 1 (+ t2 = h1·W2l^T) ----
    gather_bf16_kernel<16><<<GB, 256, 0, stream>>>(xb, row_ptr, esrc, aggb, N_NODES);
    layer1_mfma_kernel<<<LB, 256, 0, stream>>>(aggb, xb, Wb, b1, h1b, t2b, NT);

    // ---- layer 2 (gather over 128B t2 rows) ----
    gather_bf16_kernel<8><<<GB, 256, 0, stream>>>(t2b, row_ptr, esrc, agg2b, N_NODES);
    layer2_mfma_kernel<<<LB, 256, 0, stream>>>(agg2b, h1b, Wb, b2, out, NT);
}

// Round 17
// 149.292 us; speedup vs baseline: 1.3086x; 1.0789x over previous
//
#include <hip/hip_runtime.h>
#include <math.h>

#define N_NODES 50000
#define D 128       // d_in == d_hid
#define D_OUT 64

typedef short bf16x8 __attribute__((ext_vector_type(8)));   // 8 bf16 (4 VGPR) MFMA frag
typedef float f32x4  __attribute__((ext_vector_type(4)));   // MFMA accumulator
typedef unsigned short u16x8 __attribute__((ext_vector_type(8)));

__device__ __forceinline__ unsigned short f_to_bf16(float f) {
    unsigned int u = __float_as_uint(f);
    u = (u + 0x7fffu + ((u >> 16) & 1u)) >> 16;   // RNE
    return (unsigned short)u;
}
__device__ __forceinline__ float bf16lo(unsigned int v) { return __uint_as_float(v << 16); }
__device__ __forceinline__ float bf16hi(unsigned int v) { return __uint_as_float(v & 0xffff0000u); }

__device__ __forceinline__ void conv8(const float* __restrict__ src, unsigned short* __restrict__ dst, int i)
{
    float4 v0 = *reinterpret_cast<const float4*>(src + i);
    float4 v1 = *reinterpret_cast<const float4*>(src + i + 4);
    u16x8 o;
    o[0] = f_to_bf16(v0.x); o[1] = f_to_bf16(v0.y);
    o[2] = f_to_bf16(v0.z); o[3] = f_to_bf16(v0.w);
    o[4] = f_to_bf16(v1.x); o[5] = f_to_bf16(v1.y);
    o[6] = f_to_bf16(v1.z); o[7] = f_to_bf16(v1.w);
    *reinterpret_cast<u16x8*>(dst + i) = o;
}

__device__ __forceinline__ void acc_add(float* acc, uint4 v)
{
    acc[0] += bf16lo(v.x); acc[1] += bf16hi(v.x);
    acc[2] += bf16lo(v.y); acc[3] += bf16hi(v.y);
    acc[4] += bf16lo(v.z); acc[5] += bf16hi(v.z);
    acc[6] += bf16lo(v.w); acc[7] += bf16hi(v.w);
}

// ---------------------------------------------------------------------------
// Zero deg only (cursor now initialized by scan3)
// ---------------------------------------------------------------------------
__global__ __launch_bounds__(256) void zero_kernel(int* __restrict__ p, int n4)
{
    int i = blockIdx.x * 256 + threadIdx.x;
    if (i < n4) *reinterpret_cast<int4*>(p + i * 4) = make_int4(0, 0, 0, 0);
}

// ---------------------------------------------------------------------------
// Fused prep: conv_x | conv_w | hist, dispatched by block range.
// ---------------------------------------------------------------------------
__global__ __launch_bounds__(256) void prep_kernel(
    const float* __restrict__ x, unsigned short* __restrict__ xb,
    const float* __restrict__ w1l, const float* __restrict__ w1r,
    const float* __restrict__ w2l, const float* __restrict__ w2r,
    unsigned short* __restrict__ Wb,
    const int* __restrict__ dst, int* __restrict__ deg,
    int XB, int E)
{
    const int bx = blockIdx.x;
    if (bx < XB) {
        int i = (bx * 256 + threadIdx.x) * 8;
        if (i < N_NODES * D) conv8(x, xb, i);
    } else if (bx < XB + 24) {
        int i = ((bx - XB) * 256 + threadIdx.x) * 8;   // 49152 elems
        const float* src; int off;
        if      (i < 16384) { src = w1l; off = 0; }
        else if (i < 32768) { src = w1r; off = 16384; }
        else if (i < 40960) { src = w2l; off = 32768; }
        else                { src = w2r; off = 40960; }
        conv8(src, Wb + off, i - off);
    } else {
        int e = (bx - XB - 24) * 256 + threadIdx.x;
        if (e < E) atomicAdd(&deg[dst[e]], 1);
    }
}

// ---------------------------------------------------------------------------
// Scan step 1: per-block (1024 elems) local exclusive scan + block sums
// ---------------------------------------------------------------------------
__global__ __launch_bounds__(256) void scan1_kernel(
    const int* __restrict__ deg, int* __restrict__ part,
    int* __restrict__ bsum, int n)
{
    const int t = threadIdx.x;
    const int base = blockIdx.x * 1024 + t * 4;

    int a0 = 0, a1 = 0, a2 = 0, a3 = 0;
    if (base + 3 < n) {
        int4 v = *reinterpret_cast<const int4*>(deg + base);
        a0 = v.x; a1 = v.y; a2 = v.z; a3 = v.w;
    } else if (base < n) {
        a0 = deg[base];
        if (base + 1 < n) a1 = deg[base + 1];
        if (base + 2 < n) a2 = deg[base + 2];
    }
    const int s0 = a0, s1 = s0 + a1, s2 = s1 + a2, s3 = s2 + a3;

    const int lane = t & 63;
    int incl = s3;
#pragma unroll
    for (int off = 1; off < 64; off <<= 1) {
        int up = __shfl_up(incl, off);
        if (lane >= off) incl += up;
    }

    __shared__ int wsum[4];
    const int wid = t >> 6;
    if (lane == 63) wsum[wid] = incl;
    __syncthreads();

    int woff = 0;
#pragma unroll
    for (int w = 0; w < 4; ++w) woff += (w < wid) ? wsum[w] : 0;

    const int ex = woff + incl - s3;
    if (base + 3 < n) {
        int4 o; o.x = ex; o.y = ex + s0; o.z = ex + s1; o.w = ex + s2;
        *reinterpret_cast<int4*>(part + base) = o;
    } else if (base < n) {
        part[base] = ex;
        if (base + 1 < n) part[base + 1] = ex + s0;
        if (base + 2 < n) part[base + 2] = ex + s1;
    }
    if (t == 255) bsum[blockIdx.x] = woff + incl;
}

// ---------------------------------------------------------------------------
// Scan step 2: per-block offset from block sums, part+offset -> row_ptr AND
// cursor (cursor pre-initialized to bucket starts: fill uses absolute pos).
// ---------------------------------------------------------------------------
__global__ __launch_bounds__(256) void scan3_kernel(
    const int* __restrict__ part, const int* __restrict__ bsum,
    int* __restrict__ row_ptr, int* __restrict__ cursor, int nb, int n)
{
    __shared__ int sAdd, sTot;
    const int t = threadIdx.x;
    const int bid = blockIdx.x;

    if (t < 64) {
        int v   = (t < nb) ? bsum[t] : 0;
        int add = (t < bid) ? v : 0;
        int tot = v;
#pragma unroll
        for (int off = 1; off < 64; off <<= 1) {
            add += __shfl_xor(add, off);
            tot += __shfl_xor(tot, off);
        }
        if (t == 0) { sAdd = add; sTot = tot; }
    }
    __syncthreads();

    const int add = sAdd;
    const int base = bid * 1024 + t * 4;
    if (base + 3 < n) {
        int4 v = *reinterpret_cast<const int4*>(part + base);
        v.x += add; v.y += add; v.z += add; v.w += add;
        *reinterpret_cast<int4*>(row_ptr + base) = v;
        *reinterpret_cast<int4*>(cursor + base)  = v;
    } else if (base < n) {
        for (int q = 0; q < 3 && base + q < n; ++q) {
            int v = part[base + q] + add;
            row_ptr[base + q] = v;
            cursor[base + q]  = v;
        }
    }
    if (bid == nb - 1 && t == 0) row_ptr[n] = sTot;
}

// ---------------------------------------------------------------------------
// CSR bucket-fill (cursor holds absolute positions)
// ---------------------------------------------------------------------------
__global__ __launch_bounds__(256) void fill_kernel(
    const int* __restrict__ src, const int* __restrict__ dst,
    int* __restrict__ cursor, int* __restrict__ esrc, int E)
{
    int e = blockIdx.x * blockDim.x + threadIdx.x;
    if (e >= E) return;
    int pos = atomicAdd(&cursor[dst[e]], 1);
    esrc[pos] = src[e];
}

// ---------------------------------------------------------------------------
// Gather-aggregate (bf16), 1 wave/node (4 waves/block), predicated loads.
// CHUNKS=16 (256B rows): RPL=4, NLOADS=8 -> 32 rows/iter.  [r13/r16 proven]
// ---------------------------------------------------------------------------
__global__ __launch_bounds__(256) void gather_bf16_kernel(
    const unsigned short* __restrict__ xb,
    const int* __restrict__ row_ptr,
    const int* __restrict__ esrc,
    unsigned short* __restrict__ aggb,
    int n_nodes)
{
    constexpr int CHUNKS = 16;
    constexpr int RPL = 64 / CHUNKS;
    constexpr int NLOADS = 8;
    constexpr int ITER = RPL * NLOADS;
    const int wv   = threadIdx.x >> 6;
    const int lane = threadIdx.x & 63;
    const int node = blockIdx.x * 4 + wv;
    if (node >= n_nodes) return;

    const int beg = row_ptr[node];
    const int end = row_ptr[node + 1];
    const int g = lane / CHUNKS;
    const int c = lane % CHUNKS;

    const uint4* x4 = reinterpret_cast<const uint4*>(xb);

    float acc[8];
#pragma unroll
    for (int k = 0; k < 8; ++k) acc[k] = 0.f;

    for (int base = beg; base < end; base += 64) {
        const int cnt = min(end - base, 64);
        int s = (base + lane < end) ? esrc[base + lane] : 0;
        for (int i = 0; i < cnt; i += ITER) {
            int pp[NLOADS]; uint4 vv[NLOADS]; bool ok[NLOADS];
#pragma unroll
            for (int j = 0; j < NLOADS; ++j) {
                pp[j] = i + j * RPL + g;
                int sj = __shfl(s, pp[j] & 63);
                ok[j] = pp[j] < cnt;
                if (ok[j]) vv[j] = x4[(size_t)sj * CHUNKS + c];
            }
#pragma unroll
            for (int j = 0; j < NLOADS; ++j)
                if (ok[j]) acc_add(acc, vv[j]);
        }
    }

#pragma unroll
    for (int k = 0; k < 8; ++k) {
        acc[k] += __shfl_xor(acc[k], 16);
        acc[k] += __shfl_xor(acc[k], 32);
    }

    if (g == 0) {
        const float inv = (end > beg) ? 1.0f / (float)(end - beg) : 0.0f;
        uint4 o;
        o.x = (unsigned int)f_to_bf16(acc[0] * inv) | ((unsigned int)f_to_bf16(acc[1] * inv) << 16);
        o.y = (unsigned int)f_to_bf16(acc[2] * inv) | ((unsigned int)f_to_bf16(acc[3] * inv) << 16);
        o.z = (unsigned int)f_to_bf16(acc[4] * inv) | ((unsigned int)f_to_bf16(acc[5] * inv) << 16);
        o.w = (unsigned int)f_to_bf16(acc[6] * inv) | ((unsigned int)f_to_bf16(acc[7] * inv) << 16);
        reinterpret_cast<uint4*>(aggb)[(size_t)node * CHUNKS + c] = o;
    }
}

// ---------------------------------------------------------------------------
// Layer 1 — W-amortized, h1 kept in LDS ONLY (h1b eliminated).
// Block = 4 waves = 64 nodes. Stage agg+x in LDS; wave wv computes h1 slices
// jt ∈ {wv, wv+4} into Hs; barrier; then t2 = Hs·W2l^T (bf16 out) AND
// r2 = Hs·W2r^T + b2 (f32 out) with wave wv owning jt = wv for both.
// D-layout: col = lane&15, row = (lane>>4)*4 + reg   [m89 verified]
// ---------------------------------------------------------------------------
__global__ __launch_bounds__(256) void layer1_mfma_kernel(
    const unsigned short* __restrict__ aggb,
    const unsigned short* __restrict__ xb,
    const unsigned short* __restrict__ Wb,   // W1l@0, W1r@16384, W2l@32768, W2r@40960
    const float* __restrict__ b1,
    const float* __restrict__ b2,
    unsigned short* __restrict__ t2b,        // [N,64] bf16
    float* __restrict__ r2,                  // [N,64] f32
    int n_tiles)
{
    __shared__ unsigned short As[64][136];
    __shared__ unsigned short Xs[64][136];
    __shared__ unsigned short Hs[64][136];

    const int tid  = threadIdx.x;
    const int wv   = tid >> 6, lane = tid & 63;
    const int tile0 = blockIdx.x * 4;
    const int node0 = tile0 * 16;

    // ---- stage 64 agg rows + 64 x rows (coalesced, guarded) ----
    for (int q = tid; q < 1024; q += 256) {
        const int row = q >> 4, c = q & 15;
        const int node = node0 + row;
        uint4 va = make_uint4(0, 0, 0, 0), vx = va;
        if (node < N_NODES) {
            va = reinterpret_cast<const uint4*>(aggb)[(size_t)node * 16 + c];
            vx = reinterpret_cast<const uint4*>(xb)  [(size_t)node * 16 + c];
        }
        *reinterpret_cast<uint4*>(&As[row][c * 8]) = va;
        *reinterpret_cast<uint4*>(&Xs[row][c * 8]) = vx;
    }
    __syncthreads();

    const int c16 = lane & 15, kg = lane >> 4;

    // ---- h1: wave wv computes jt = wv and wv+4 for all 4 tiles (LDS only) ----
#pragma unroll
    for (int jj = 0; jj < 2; ++jj) {
        const int jt = wv + jj * 4;
        bf16x8 wlf[4], wrf[4];
        {
            const unsigned short* wl = Wb +         (size_t)(jt * 16 + c16) * D + kg * 8;
            const unsigned short* wr = Wb + 16384 + (size_t)(jt * 16 + c16) * D + kg * 8;
#pragma unroll
            for (int kf = 0; kf < 4; ++kf) {
                wlf[kf] = *reinterpret_cast<const bf16x8*>(wl + kf * 32);
                wrf[kf] = *reinterpret_cast<const bf16x8*>(wr + kf * 32);
            }
        }
        const float bias = b1[jt * 16 + c16];

#pragma unroll
        for (int t = 0; t < 4; ++t) {
            if (tile0 + t < n_tiles) {
                const int r0 = t * 16;
                f32x4 acc = {0.f, 0.f, 0.f, 0.f};
#pragma unroll
                for (int kf = 0; kf < 4; ++kf) {
                    bf16x8 a0 = *reinterpret_cast<const bf16x8*>(&As[r0 + c16][kg * 8 + kf * 32]);
                    acc = __builtin_amdgcn_mfma_f32_16x16x32_bf16(a0, wlf[kf], acc, 0, 0, 0);
                }
#pragma unroll
                for (int kf = 0; kf < 4; ++kf) {
                    bf16x8 a1 = *reinterpret_cast<const bf16x8*>(&Xs[r0 + c16][kg * 8 + kf * 32]);
                    acc = __builtin_amdgcn_mfma_f32_16x16x32_bf16(a1, wrf[kf], acc, 0, 0, 0);
                }
#pragma unroll
                for (int i = 0; i < 4; ++i) {
                    const int row = r0 + kg * 4 + i;
                    float v = fmaxf(acc[i] + bias, 0.0f);
                    Hs[row][jt * 16 + c16] = f_to_bf16(v);
                }
            }
        }
    }
    __syncthreads();

    // ---- t2 = Hs·W2l^T (bf16) and r2 = Hs·W2r^T + b2 (f32): jt = wv ----
    {
        const int jt = wv;
        bf16x8 w2l[4], w2r[4];
        {
            const unsigned short* wl = Wb + 32768 + (size_t)(jt * 16 + c16) * D + kg * 8;
            const unsigned short* wr = Wb + 40960 + (size_t)(jt * 16 + c16) * D + kg * 8;
#pragma unroll
            for (int kf = 0; kf < 4; ++kf) {
                w2l[kf] = *reinterpret_cast<const bf16x8*>(wl + kf * 32);
                w2r[kf] = *reinterpret_cast<const bf16x8*>(wr + kf * 32);
            }
        }
        const float bias2 = b2[jt * 16 + c16];

#pragma unroll
        for (int t = 0; t < 4; ++t) {
            if (tile0 + t < n_tiles) {
                const int r0 = t * 16;
                bf16x8 af[4];
#pragma unroll
                for (int kf = 0; kf < 4; ++kf)
                    af[kf] = *reinterpret_cast<const bf16x8*>(&Hs[r0 + c16][kg * 8 + kf * 32]);

                f32x4 accT = {0.f, 0.f, 0.f, 0.f};
                f32x4 accR = {0.f, 0.f, 0.f, 0.f};
#pragma unroll
                for (int kf = 0; kf < 4; ++kf) {
                    accT = __builtin_amdgcn_mfma_f32_16x16x32_bf16(af[kf], w2l[kf], accT, 0, 0, 0);
                    accR = __builtin_amdgcn_mfma_f32_16x16x32_bf16(af[kf], w2r[kf], accR, 0, 0, 0);
                }
#pragma unroll
                for (int i = 0; i < 4; ++i) {
                    const int node = node0 + r0 + kg * 4 + i;
                    t2b[(size_t)node * D_OUT + jt * 16 + c16] = f_to_bf16(accT[i]);
                    r2 [(size_t)node * D_OUT + jt * 16 + c16] = accR[i] + bias2;
                }
            }
        }
    }
}

// ---------------------------------------------------------------------------
// Fused gather(t2, 128B rows) + add r2 + log_softmax -> out.
// 1 wave/node, 4 waves/block. After the xor-reduce every lane holds the full
// premeaned 8-elem slice; lanes 0..7 (g==0) add r2, softmax across 8 lanes
// (xor 1,2,4), write 64 f32 (2x float4 per lane, 256B/node contiguous).
// ---------------------------------------------------------------------------
__global__ __launch_bounds__(256) void gather2_sm_kernel(
    const unsigned short* __restrict__ t2b,
    const float* __restrict__ r2,
    const int* __restrict__ row_ptr,
    const int* __restrict__ esrc,
    float* __restrict__ out,
    int n_nodes)
{
    constexpr int CHUNKS = 8;               // 128B bf16 rows
    constexpr int RPL = 64 / CHUNKS;        // 8 rows per load
    constexpr int NLOADS = 8;
    constexpr int ITER = RPL * NLOADS;      // 64 rows/iter
    const int wv   = threadIdx.x >> 6;
    const int lane = threadIdx.x & 63;
    const int node = blockIdx.x * 4 + wv;
    if (node >= n_nodes) return;

    const int beg = row_ptr[node];
    const int end = row_ptr[node + 1];
    const int g = lane / CHUNKS;
    const int c = lane % CHUNKS;

    const uint4* t4 = reinterpret_cast<const uint4*>(t2b);

    float acc[8];
#pragma unroll
    for (int k = 0; k < 8; ++k) acc[k] = 0.f;

    for (int base = beg; base < end; base += 64) {
        const int cnt = min(end - base, 64);
        int s = (base + lane < end) ? esrc[base + lane] : 0;
        for (int i = 0; i < cnt; i += ITER) {
            int pp[NLOADS]; uint4 vv[NLOADS]; bool ok[NLOADS];
#pragma unroll
            for (int j = 0; j < NLOADS; ++j) {
                pp[j] = i + j * RPL + g;
                int sj = __shfl(s, pp[j] & 63);
                ok[j] = pp[j] < cnt;
                if (ok[j]) vv[j] = t4[(size_t)sj * CHUNKS + c];
            }
#pragma unroll
            for (int j = 0; j < NLOADS; ++j)
                if (ok[j]) acc_add(acc, vv[j]);
        }
    }

    // full reduce over g: every lane ends with the complete sums for chunk c
#pragma unroll
    for (int k = 0; k < 8; ++k) {
        acc[k] += __shfl_xor(acc[k], 8);
        acc[k] += __shfl_xor(acc[k], 16);
        acc[k] += __shfl_xor(acc[k], 32);
    }

    const float inv = (end > beg) ? 1.0f / (float)(end - beg) : 0.0f;

    // z = mean + r2 (bias already folded into r2); all lanes compute (dup by g)
    float4 ra = *reinterpret_cast<const float4*>(r2 + (size_t)node * D_OUT + c * 8);
    float4 rb = *reinterpret_cast<const float4*>(r2 + (size_t)node * D_OUT + c * 8 + 4);
    float z[8];
    z[0] = acc[0] * inv + ra.x; z[1] = acc[1] * inv + ra.y;
    z[2] = acc[2] * inv + ra.z; z[3] = acc[3] * inv + ra.w;
    z[4] = acc[4] * inv + rb.x; z[5] = acc[5] * inv + rb.y;
    z[6] = acc[6] * inv + rb.z; z[7] = acc[7] * inv + rb.w;

    // softmax over 64 outputs: local 8 + xor reduce over the 8 c-lanes
    float m = z[0];
#pragma unroll
    for (int k = 1; k < 8; ++k) m = fmaxf(m, z[k]);
#pragma unroll
    for (int off = 1; off < 8; off <<= 1)
        m = fmaxf(m, __shfl_xor(m, off));
    float s = 0.f;
#pragma unroll
    for (int k = 0; k < 8; ++k) s += expf(z[k] - m);
#pragma unroll
    for (int off = 1; off < 8; off <<= 1)
        s += __shfl_xor(s, off);
    const float lse = m + logf(s);

    if (g == 0) {
        float4 oa, ob;
        oa.x = z[0] - lse; oa.y = z[1] - lse; oa.z = z[2] - lse; oa.w = z[3] - lse;
        ob.x = z[4] - lse; ob.y = z[5] - lse; ob.z = z[6] - lse; ob.w = z[7] - lse;
        *reinterpret_cast<float4*>(out + (size_t)node * D_OUT + c * 8)     = oa;
        *reinterpret_cast<float4*>(out + (size_t)node * D_OUT + c * 8 + 4) = ob;
    }
}

// ---------------------------------------------------------------------------
extern "C" void kernel_launch(void* const* d_in, const int* in_sizes, int n_in,
                              void* d_out, int out_size, void* d_ws, size_t ws_size,
                              hipStream_t stream)
{
    const float* x   = (const float*)d_in[0];
    const int*   ei  = (const int*)d_in[1];
    const float* W1l = (const float*)d_in[2];
    const float* b1  = (const float*)d_in[3];
    const float* W1r = (const float*)d_in[4];
    const float* W2l = (const float*)d_in[5];
    const float* b2  = (const float*)d_in[6];
    const float* W2r = (const float*)d_in[7];
    float* out = (float*)d_out;

    const int E = in_sizes[1] / 2;
    const int* src = ei;
    const int* dst = ei + E;

    // ---- workspace layout (256B-aligned chunks) ----
    char* base = (char*)d_ws;
    size_t off = 0;
    auto take = [&](size_t bytes) { char* p = base + off; off += (bytes + 255) & ~(size_t)255; return p; };

    unsigned short* xb   = (unsigned short*)take((size_t)N_NODES * D * 2);
    unsigned short* aggb = (unsigned short*)take((size_t)N_NODES * D * 2);
    unsigned short* t2b  = (unsigned short*)take((size_t)N_NODES * D_OUT * 2);
    float*          r2   = (float*)         take((size_t)N_NODES * D_OUT * 4);
    unsigned short* Wb   = (unsigned short*)take((size_t)49152 * 2);
    int* deg     = (int*)take((size_t)N_NODES * 4);
    int* cursor  = (int*)take((size_t)N_NODES * 4);
    int* row_ptr = (int*)take(((size_t)N_NODES + 1) * 4);
    int* part    = (int*)take((size_t)N_NODES * 4);
    int* bsum    = (int*)take((size_t)64 * 4);
    int* esrc    = (int*)take((size_t)E * 4);

    const int EB = (E + 255) / 256;
    const int SB = (N_NODES + 1023) / 1024;       // 49 scan blocks
    const int XB = (N_NODES * D / 8 + 255) / 256; // 3125 conv_x blocks
    const int GB = (N_NODES + 3) / 4;             // gather: 4 nodes per block
    const int NT = N_NODES / 16;                  // 3125 MFMA tiles, exact
    const int LB = (NT + 3) / 4;                  // 782 layer blocks (64 nodes each)

    zero_kernel<<<(N_NODES / 4 + 255) / 256, 256, 0, stream>>>(deg, N_NODES / 4);
    prep_kernel<<<XB + 24 + EB, 256, 0, stream>>>(x, xb, W1l, W1r, W2l, W2r, Wb, dst, deg, XB, E);
    scan1_kernel<<<SB, 256, 0, stream>>>(deg, part, bsum, N_NODES);
    scan3_kernel<<<SB, 256, 0, stream>>>(part, bsum, row_ptr, cursor, SB, N_NODES);
    fill_kernel<<<EB, 256, 0, stream>>>(src, dst, cursor, esrc, E);

    // ---- layer 1 (h1 LDS-only; emits t2 bf16 + r2 f32) ----
    gather_bf16_kernel<<<GB, 256, 0, stream>>>(xb, row_ptr, esrc, aggb, N_NODES);
    layer1_mfma_kernel<<<LB, 256, 0, stream>>>(aggb, xb, Wb, b1, b2, t2b, r2, NT);

    // ---- fused gather(t2) + r2 + log_softmax ----
    gather2_sm_kernel<<<GB, 256, 0, stream>>>(t2b, r2, row_ptr, esrc, out, N_NODES);
}